// Round 5
// baseline (108.039 us; speedup 1.0000x reference)
//
#include <hip/hip_runtime.h>
#include <cstdint>

// B=4, N=256, D=128, HID=128, IN_DIM=516.
// G[i,j,h] = [|hi-hj| ; hi*hj] @ W1[256:512]   (K=256 fp8 MFMA GEMM, W x256) -- SYMMETRIC in (i,j)
// L[i,j]   = relu(G/256 + PiB[i,h] + Pjf[j,h] + scal(i,j)w) @ W2 + b2
// out[i,j] = out[j,i] = 0.5*(L[i,j]+L[j,i]) ; diag = -1e9.
// Blocks cover unordered 8x8 tile-pairs (I<=J): G computed once, two epilogues.

typedef float f32x4 __attribute__((ext_vector_type(4)));

#define INV256 0.00390625f

__device__ __forceinline__ uint32_t pk4(float a, float b, float c, float d) {
  uint32_t u = __builtin_amdgcn_cvt_pk_fp8_f32(a, b, 0, false);
  u = __builtin_amdgcn_cvt_pk_fp8_f32(c, d, u, true);
  return u;
}
__device__ __forceinline__ long mk64(uint32_t lo, uint32_t hi) {
  return (long)((((unsigned long long)hi) << 32) | lo);
}

// bid<32: pack fp8 B-image (lane-linear MFMA fragment order, values W1*256)
// bid in [32,1056): PiB = node@W1[0:128] + b1 ; Pjf = node@W1[128:256]  (both fp32)
__global__ __launch_bounds__(128) void pre_k(const float* __restrict__ node,
                                             const float* __restrict__ W1,
                                             const float* __restrict__ b1,
                                             float* __restrict__ PiB,
                                             float* __restrict__ Pjf,
                                             uint32_t* __restrict__ W1f8) {
  int bid = blockIdx.x;
  int tid = threadIdx.x;
  if (bid < 32) {
    int ks = bid >> 2, nip = (bid >> 1) & 1, wn = bid & 1;
    int lane = tid & 63, nilow = tid >> 6;
    int quad = lane >> 4, col = lane & 15;
    int h = wn * 64 + (nip * 2 + nilow) * 16 + col;
    int k0 = ks * 32 + quad * 8;
    float w[8];
#pragma unroll
    for (int t = 0; t < 8; ++t) w[t] = W1[(256 + k0 + t) * 128 + h] * 256.0f;
    uint2 u;
    u.x = pk4(w[0], w[1], w[2], w[3]);
    u.y = pk4(w[4], w[5], w[6], w[7]);
    reinterpret_cast<uint2*>(W1f8)[(bid * 64 + lane) * 2 + nilow] = u;
  } else {
    __shared__ float sN[128];
    int row = bid - 32;  // 0..1023
    int h = tid;
    sN[h] = node[row * 128 + h];
    __syncthreads();
    float ai = 0.f, aj = 0.f;
#pragma unroll 8
    for (int d = 0; d < 128; ++d) {
      float v = sN[d];
      ai = fmaf(v, W1[d * 128 + h], ai);
      aj = fmaf(v, W1[(128 + d) * 128 + h], aj);
    }
    PiB[row * 128 + h] = ai + b1[h];
    Pjf[row * 128 + h] = aj;
  }
}

// grid 2112 = b(4) * 528 unordered tile-pairs (32 groups of 8 rows, I<=J).
// 64 pairs p=(ii,jj) per block, K=256 fp8, N=128 h. Two epilogues (fwd+mirror).
__global__ __launch_bounds__(256, 3) void main_k(
    const float* __restrict__ node, const float* __restrict__ baseL,
    const float* __restrict__ compL, const float* __restrict__ W1,
    const float* __restrict__ W2, const float* __restrict__ b2,
    const uint32_t* __restrict__ W1f8, const float* __restrict__ PiB,
    const float* __restrict__ Pjf, float* __restrict__ out) {
  // smem: [sF 16640 | sB 32768]; sB region doubles as sNode (8KB) before B-commit,
  // and as sPM (8448) after MFMA; sF doubles as sPF after MFMA.
  __shared__ __align__(16) char smem[16640 + 32768];
  __shared__ float sScalF[64][4];
  __shared__ float sScalM[64][4];
  char* sF = smem;
  char* sB = smem + 16640;
  float* sNode = reinterpret_cast<float*>(sB);  // 16 rows x 128 fp32

  const int tid = threadIdx.x;
  const int bx = blockIdx.x;
  const int b = bx / 528;
  const int t = bx - b * 528;
  // decode unordered pair: offset(x) = (65x - x^2)/2, tI = max x with offset<=t
  int tI = (int)((65.0f - sqrtf(4225.0f - 8.0f * (float)t)) * 0.5f);
  tI = (tI < 0) ? 0 : (tI > 31 ? 31 : tI);
  while (((65 * tI - tI * tI) >> 1) > t) --tI;
  while (tI < 31 && ((65 * (tI + 1) - (tI + 1) * (tI + 1)) >> 1) <= t) ++tI;
  const int tJ = tI + (t - ((65 * tI - tI * tI) >> 1));
  const int I0 = tI * 8, J0 = tJ * 8;
  const int rowB = b * 256;

  const int lane = tid & 63;
  const int wave = tid >> 6;
  const int wm = wave >> 1, wn = wave & 1;
  const int col = lane & 15, quad = lane >> 4;

  // ---- B image to registers (committed to LDS after F-build) ----
  uint4 g[8];
#pragma unroll
  for (int it = 0; it < 8; ++it)
    g[it] = reinterpret_cast<const uint4*>(W1f8)[it * 256 + tid];

  // ---- stage 16 node rows (I-group then J-group) into sNode ----
#pragma unroll
  for (int it = 0; it < 2; ++it) {
    int idx = it * 256 + tid;  // 512 float4 slots
    int row = idx >> 5, d4 = idx & 31;
    int gr = rowB + ((row < 8) ? (I0 + row) : (J0 + row - 8));
    reinterpret_cast<float4*>(sNode)[idx] =
        reinterpret_cast<const float4*>(node + (size_t)gr * 128)[d4];
  }

  // ---- scalar features, forward (tid<64) and mirror (tid in [64,128)) ----
  if (tid < 128) {
    int p = tid & 63;
    int mir = tid >> 6;
    int iN = I0 + (p >> 3), jN = J0 + (p & 7);
    int rr = mir ? jN : iN, cc = mir ? iN : jN;
    float bl = fminf(fmaxf(baseL[(size_t)(rowB + rr) * 256 + cc], -20.f), 20.f);
    float cl = fminf(fmaxf(compL[(size_t)(rowB + rr) * 256 + cc], -20.f), 20.f);
    float* dst = mir ? sScalM[p] : sScalF[p];
    dst[0] = bl;
    dst[1] = 1.f / (1.f + __expf(-bl));
    dst[2] = cl;
    dst[3] = 1.f / (1.f + __expf(-cl));
  }

  // ---- epilogue constants ----
  float cW2[4], cB0[4], cB1[4], cB2[4], cB3[4];
#pragma unroll
  for (int ni = 0; ni < 4; ++ni) {
    int h = wn * 64 + ni * 16 + col;
    cW2[ni] = W2[h];
    cB0[ni] = W1[512 * 128 + h];
    cB1[ni] = W1[513 * 128 + h];
    cB2[ni] = W1[514 * 128 + h];
    cB3[ni] = W1[515 * 128 + h];
  }
  const float b2v = b2[0];

  // ---- Pi/Pj rows this lane needs in the epilogue (L2-hot, issued early) ----
  // for lane's pairs p = wm*32+mi*16+quad*4+r: ii(p)=wm*4+mi*2+(quad>>1), jj(p)=(quad&1)*4+r
  float piI[2][4], pjI[2][4], piJ[4][4], pjJ[4][4];
#pragma unroll
  for (int mi = 0; mi < 2; ++mi) {
    int gi = rowB + I0 + wm * 4 + mi * 2 + (quad >> 1);
#pragma unroll
    for (int ni = 0; ni < 4; ++ni) {
      int h = wn * 64 + ni * 16 + col;
      piI[mi][ni] = PiB[(size_t)gi * 128 + h];
      pjI[mi][ni] = Pjf[(size_t)gi * 128 + h];
    }
  }
#pragma unroll
  for (int r = 0; r < 4; ++r) {
    int gj = rowB + J0 + (quad & 1) * 4 + r;
#pragma unroll
    for (int ni = 0; ni < 4; ++ni) {
      int h = wn * 64 + ni * 16 + col;
      piJ[r][ni] = PiB[(size_t)gj * 128 + h];
      pjJ[r][ni] = Pjf[(size_t)gj * 128 + h];
    }
  }
  __syncthreads();

  // ---- F-build: 64 pairs x 256 k fp8, A-fragment order. p = pass*8 + rr ----
  {
    const int d4 = tid & 31;
    const int rr = tid >> 5;  // = jj for this thread's pairs
    const int ks1 = d4 >> 3, qj = (d4 >> 1) & 3, kb = (d4 & 1) * 4;
    const float4 hj = reinterpret_cast<const float4*>(sNode + (8 + rr) * 128)[d4];
#pragma unroll
    for (int pass = 0; pass < 8; ++pass) {
      const float4 hi = reinterpret_cast<const float4*>(sNode + pass * 128)[d4];
      uint32_t du = pk4(fabsf(hi.x - hj.x), fabsf(hi.y - hj.y),
                        fabsf(hi.z - hj.z), fabsf(hi.w - hj.w));
      uint32_t pu = pk4(hi.x * hj.x, hi.y * hj.y, hi.z * hj.z, hi.w * hj.w);
      int p = pass * 8 + rr;
      int colj = p & 15, m16 = p >> 4;
      int off = (m16 >> 1) * 1024 + (qj * 16 + colj) * 16 + (m16 & 1) * 8 + kb;
      *reinterpret_cast<uint32_t*>(sF + ks1 * 2080 + off) = du;
      *reinterpret_cast<uint32_t*>(sF + (4 + ks1) * 2080 + off) = pu;
    }
  }
  __syncthreads();  // sNode dead; commit B image over it
#pragma unroll
  for (int it = 0; it < 8; ++it)
    reinterpret_cast<uint4*>(sB)[it * 256 + tid] = g[it];
  __syncthreads();

  // ---- MFMA: G[64 pairs][128 h], K=256, all frag reads lane-linear ----
  f32x4 acc[2][4] = {};
#pragma unroll
  for (int ks = 0; ks < 8; ++ks) {
    uint4 b01 = *reinterpret_cast<const uint4*>(sB + ((ks * 2 + 0) * 2 + wn) * 1024 + lane * 16);
    uint4 b23 = *reinterpret_cast<const uint4*>(sB + ((ks * 2 + 1) * 2 + wn) * 1024 + lane * 16);
    uint4 aa = *reinterpret_cast<const uint4*>(sF + ks * 2080 + wm * 1024 + lane * 16);
    long a0 = mk64(aa.x, aa.y), a1 = mk64(aa.z, aa.w);
    long bb0 = mk64(b01.x, b01.y), bb1 = mk64(b01.z, b01.w);
    long bb2 = mk64(b23.x, b23.y), bb3 = mk64(b23.z, b23.w);
    acc[0][0] = __builtin_amdgcn_mfma_f32_16x16x32_fp8_fp8(a0, bb0, acc[0][0], 0, 0, 0);
    acc[0][1] = __builtin_amdgcn_mfma_f32_16x16x32_fp8_fp8(a0, bb1, acc[0][1], 0, 0, 0);
    acc[0][2] = __builtin_amdgcn_mfma_f32_16x16x32_fp8_fp8(a0, bb2, acc[0][2], 0, 0, 0);
    acc[0][3] = __builtin_amdgcn_mfma_f32_16x16x32_fp8_fp8(a0, bb3, acc[0][3], 0, 0, 0);
    acc[1][0] = __builtin_amdgcn_mfma_f32_16x16x32_fp8_fp8(a1, bb0, acc[1][0], 0, 0, 0);
    acc[1][1] = __builtin_amdgcn_mfma_f32_16x16x32_fp8_fp8(a1, bb1, acc[1][1], 0, 0, 0);
    acc[1][2] = __builtin_amdgcn_mfma_f32_16x16x32_fp8_fp8(a1, bb2, acc[1][2], 0, 0, 0);
    acc[1][3] = __builtin_amdgcn_mfma_f32_16x16x32_fp8_fp8(a1, bb3, acc[1][3], 0, 0, 0);
  }

  __syncthreads();  // sF/sB dead -> partial-sum buffers
  float(*sPF)[33] = reinterpret_cast<float(*)[33]>(smem);           // 8448 B in sF region
  float(*sPM)[33] = reinterpret_cast<float(*)[33]>(smem + 16640);   // 8448 B in sB region

  // ---- two epilogues per pair: fwd L(i,j) and mirror L(j,i); op order symmetric ----
#pragma unroll
  for (int mi = 0; mi < 2; ++mi) {
#pragma unroll
    for (int r = 0; r < 4; ++r) {
      int p = wm * 32 + mi * 16 + quad * 4 + r;  // C/D: row = quad*4 + reg
      float f0 = sScalF[p][0], f1 = sScalF[p][1], f2 = sScalF[p][2], f3 = sScalF[p][3];
      float m0 = sScalM[p][0], m1 = sScalM[p][1], m2 = sScalM[p][2], m3 = sScalM[p][3];
      float vf = 0.f, vm = 0.f;
#pragma unroll
      for (int ni = 0; ni < 4; ++ni) {
        float gv = acc[mi][ni][r] * INV256;
        float pf = (gv + piI[mi][ni]) + pjJ[r][ni];
        pf = fmaf(f0, cB0[ni], pf);
        pf = fmaf(f1, cB1[ni], pf);
        pf = fmaf(f2, cB2[ni], pf);
        pf = fmaf(f3, cB3[ni], pf);
        float pm = (gv + piJ[r][ni]) + pjI[mi][ni];
        pm = fmaf(m0, cB0[ni], pm);
        pm = fmaf(m1, cB1[ni], pm);
        pm = fmaf(m2, cB2[ni], pm);
        pm = fmaf(m3, cB3[ni], pm);
        vf = fmaf(fmaxf(pf, 0.f), cW2[ni], vf);
        vm = fmaf(fmaxf(pm, 0.f), cW2[ni], vm);
      }
      sPF[p][wn * 16 + col] = vf;
      sPM[p][wn * 16 + col] = vm;
    }
  }
  __syncthreads();
  if (tid < 64) {
    int p = tid;
    float sumF = 0.f, sumM = 0.f;
#pragma unroll
    for (int c = 0; c < 32; ++c) {
      sumF += sPF[p][c];
      sumM += sPM[p][c];
    }
    float val = 0.5f * (sumF + sumM) + b2v;
    int iN = I0 + (p >> 3), jN = J0 + (p & 7);
    if (iN == jN) {
      out[(size_t)(rowB + iN) * 256 + jN] = -1e9f;
    } else {
      out[(size_t)(rowB + iN) * 256 + jN] = val;
      out[(size_t)(rowB + jN) * 256 + iN] = val;
    }
  }
}

extern "C" void kernel_launch(void* const* d_in, const int* in_sizes, int n_in,
                              void* d_out, int out_size, void* d_ws, size_t ws_size,
                              hipStream_t stream) {
  const float* node = (const float*)d_in[0];   // [4,256,128]
  const float* baseL = (const float*)d_in[1];  // [4,256,256]
  const float* compL = (const float*)d_in[2];  // [4,256,256]
  const float* W1 = (const float*)d_in[3];     // [516,128]
  const float* b1 = (const float*)d_in[4];     // [128]
  const float* W2 = (const float*)d_in[5];     // [128,1]
  const float* b2 = (const float*)d_in[6];     // [1]
  float* out = (float*)d_out;                  // [4,256,256] fp32

  char* ws = (char*)d_ws;
  float* PiB = (float*)(ws);                              // 512 KB
  float* Pjf = (float*)(ws + (512 << 10));                // 512 KB
  uint32_t* W1f8 = (uint32_t*)(ws + (1024 << 10));        // 32 KB

  pre_k<<<1056, 128, 0, stream>>>(node, W1, b1, PiB, Pjf, W1f8);
  main_k<<<2112, 256, 0, stream>>>(node, baseL, compL, W1, W2, b2, W1f8, PiB, Pjf, out);
}

// Round 6
// 98.466 us; speedup vs baseline: 1.0972x; 1.0972x over previous
//
#include <hip/hip_runtime.h>
#include <cstdint>

// B=4, N=256, D=128, HID=128, IN_DIM=516.
// G[i,j,h] = [|hi-hj| ; hi*hj] @ W1[256:512]   (K=256 fp8 MFMA GEMM, W x256) -- SYMMETRIC in (i,j)
// L[i,j]   = relu(G/256 + PiB[i,h] + Pjf[j,h] + scal(i,j)w) @ W2 + b2
// out[i,j] = out[j,i] = 0.5*(L[i,j]+L[j,i]) ; diag = -1e9.
// Blocks cover unordered 8x8 tile-pairs (I<=J): G computed once, two epilogues.
// R6: B streamed from global (L2 broadcast, no sB); Pi/Pj staged to LDS coalesced
//     (R5's register-held scattered loads were sunk into the epilogue by the
//      compiler at VGPR=68 -> serialized latency). LDS 51.7->36.9 KB, 4 blocks/CU.

typedef float f32x4 __attribute__((ext_vector_type(4)));

#define INV256 0.00390625f

__device__ __forceinline__ uint32_t pk4(float a, float b, float c, float d) {
  uint32_t u = __builtin_amdgcn_cvt_pk_fp8_f32(a, b, 0, false);
  u = __builtin_amdgcn_cvt_pk_fp8_f32(c, d, u, true);
  return u;
}
__device__ __forceinline__ uint32_t pkbf2(float lo, float hi) {
  uint32_t l = __builtin_bit_cast(uint32_t, lo);
  uint32_t h = __builtin_bit_cast(uint32_t, hi);
  return (l >> 16) | (h & 0xffff0000u);
}
__device__ __forceinline__ float bf2f(unsigned short u) {
  uint32_t x = ((uint32_t)u) << 16;
  return __builtin_bit_cast(float, x);
}
__device__ __forceinline__ long mk64(uint32_t lo, uint32_t hi) {
  return (long)((((unsigned long long)hi) << 32) | lo);
}

// bid<32: pack fp8 B-image (lane-linear MFMA fragment order, values W1*256)
// bid in [32,1056): PiB = node@W1[0:128] + b1 ; Pjf = node@W1[128:256]  (both fp32)
__global__ __launch_bounds__(128) void pre_k(const float* __restrict__ node,
                                             const float* __restrict__ W1,
                                             const float* __restrict__ b1,
                                             float* __restrict__ PiB,
                                             float* __restrict__ Pjf,
                                             uint32_t* __restrict__ W1f8) {
  int bid = blockIdx.x;
  int tid = threadIdx.x;
  if (bid < 32) {
    int ks = bid >> 2, nip = (bid >> 1) & 1, wn = bid & 1;
    int lane = tid & 63, nilow = tid >> 6;
    int quad = lane >> 4, col = lane & 15;
    int h = wn * 64 + (nip * 2 + nilow) * 16 + col;
    int k0 = ks * 32 + quad * 8;
    float w[8];
#pragma unroll
    for (int t = 0; t < 8; ++t) w[t] = W1[(256 + k0 + t) * 128 + h] * 256.0f;
    uint2 u;
    u.x = pk4(w[0], w[1], w[2], w[3]);
    u.y = pk4(w[4], w[5], w[6], w[7]);
    reinterpret_cast<uint2*>(W1f8)[(bid * 64 + lane) * 2 + nilow] = u;
  } else {
    __shared__ float sN[128];
    int row = bid - 32;  // 0..1023
    int h = tid;
    sN[h] = node[row * 128 + h];
    __syncthreads();
    float ai = 0.f, aj = 0.f;
#pragma unroll 8
    for (int d = 0; d < 128; ++d) {
      float v = sN[d];
      ai = fmaf(v, W1[d * 128 + h], ai);
      aj = fmaf(v, W1[(128 + d) * 128 + h], aj);
    }
    PiB[row * 128 + h] = ai + b1[h];
    Pjf[row * 128 + h] = aj;
  }
}

// grid 2112 = b(4) * 528 unordered tile-pairs (32 groups of 8 rows, I<=J).
__global__ __launch_bounds__(256, 4) void main_k(
    const float* __restrict__ node, const float* __restrict__ baseL,
    const float* __restrict__ compL, const float* __restrict__ W1,
    const float* __restrict__ W2, const float* __restrict__ b2,
    const uint32_t* __restrict__ W1f8, const float* __restrict__ PiB,
    const float* __restrict__ Pjf, float* __restrict__ out) {
  // smem[0:16640]   = sF (fp8 A-image), reused as sPF (64x33 fp32) post-MFMA
  // smem[16640:25088] = sNode (16x128 fp32, dead after F-build), reused as sPM
  __shared__ __align__(16) char smem[25088];
  __shared__ unsigned short sPP[32 * 136];  // bf16: rows 0-7 PiB_I,8-15 PiB_J,16-23 Pjf_I,24-31 Pjf_J
  __shared__ float sScalF[64][4];
  __shared__ float sScalM[64][4];
  char* sF = smem;
  float* sNode = reinterpret_cast<float*>(smem + 16640);

  const int tid = threadIdx.x;
  const int bx = blockIdx.x;
  const int b = bx / 528;
  const int t = bx - b * 528;
  int tI = (int)((65.0f - sqrtf(4225.0f - 8.0f * (float)t)) * 0.5f);
  tI = (tI < 0) ? 0 : (tI > 31 ? 31 : tI);
  while (((65 * tI - tI * tI) >> 1) > t) --tI;
  while (tI < 31 && ((65 * (tI + 1) - (tI + 1) * (tI + 1)) >> 1) <= t) ++tI;
  const int tJ = tI + (t - ((65 * tI - tI * tI) >> 1));
  const int I0 = tI * 8, J0 = tJ * 8;
  const int rowB = b * 256;

  const int lane = tid & 63;
  const int wave = tid >> 6;
  const int wm = wave >> 1, wn = wave & 1;
  const int col = lane & 15, quad = lane >> 4;

  // ---- stage 16 node rows (I-group then J-group), coalesced ----
#pragma unroll
  for (int it = 0; it < 2; ++it) {
    int idx = it * 256 + tid;
    int row = idx >> 5, d4 = idx & 31;
    int gr = rowB + ((row < 8) ? (I0 + row) : (J0 + row - 8));
    reinterpret_cast<float4*>(sNode)[idx] =
        reinterpret_cast<const float4*>(node + (size_t)gr * 128)[d4];
  }

  // ---- stage Pi/Pj rows (coalesced float4 -> bf16 LDS); consumed in epilogue ----
#pragma unroll
  for (int it = 0; it < 4; ++it) {
    int idx = it * 256 + tid;  // 1024 float4 slots = 32 rows x 32
    int row = idx >> 5, d4 = idx & 31;
    int rr = row & 15;
    const float* src = (row < 16) ? PiB : Pjf;
    int gr = rowB + ((rr < 8) ? (I0 + rr) : (J0 + rr - 8));
    float4 v = reinterpret_cast<const float4*>(src + (size_t)gr * 128)[d4];
    uint2 u;
    u.x = pkbf2(v.x, v.y);
    u.y = pkbf2(v.z, v.w);
    *reinterpret_cast<uint2*>(&sPP[row * 136 + d4 * 4]) = u;
  }

  // ---- scalar features, forward (tid<64) and mirror (tid in [64,128)) ----
  if (tid < 128) {
    int p = tid & 63;
    int mir = tid >> 6;
    int iN = I0 + (p >> 3), jN = J0 + (p & 7);
    int rr = mir ? jN : iN, cc = mir ? iN : jN;
    float bl = fminf(fmaxf(baseL[(size_t)(rowB + rr) * 256 + cc], -20.f), 20.f);
    float cl = fminf(fmaxf(compL[(size_t)(rowB + rr) * 256 + cc], -20.f), 20.f);
    float* dst = mir ? sScalM[p] : sScalF[p];
    dst[0] = bl;
    dst[1] = 1.f / (1.f + __expf(-bl));
    dst[2] = cl;
    dst[3] = 1.f / (1.f + __expf(-cl));
  }

  // ---- epilogue constants (small, L2-hot) ----
  float cW2[4], cB0[4], cB1[4], cB2[4], cB3[4];
#pragma unroll
  for (int ni = 0; ni < 4; ++ni) {
    int h = wn * 64 + ni * 16 + col;
    cW2[ni] = W2[h];
    cB0[ni] = W1[512 * 128 + h];
    cB1[ni] = W1[513 * 128 + h];
    cB2[ni] = W1[514 * 128 + h];
    cB3[ni] = W1[515 * 128 + h];
  }
  const float b2v = b2[0];
  __syncthreads();

  // ---- F-build: 64 pairs x 256 k fp8, A-fragment order. p = pass*8 + rr ----
  {
    const int d4 = tid & 31;
    const int rr = tid >> 5;  // = jj for this thread's pairs
    const int ks1 = d4 >> 3, qj = (d4 >> 1) & 3, kb = (d4 & 1) * 4;
    const float4 hj = reinterpret_cast<const float4*>(sNode + (8 + rr) * 128)[d4];
#pragma unroll
    for (int pass = 0; pass < 8; ++pass) {
      const float4 hi = reinterpret_cast<const float4*>(sNode + pass * 128)[d4];
      uint32_t du = pk4(fabsf(hi.x - hj.x), fabsf(hi.y - hj.y),
                        fabsf(hi.z - hj.z), fabsf(hi.w - hj.w));
      uint32_t pu = pk4(hi.x * hj.x, hi.y * hj.y, hi.z * hj.z, hi.w * hj.w);
      int p = pass * 8 + rr;
      int colj = p & 15, m16 = p >> 4;
      int off = (m16 >> 1) * 1024 + (qj * 16 + colj) * 16 + (m16 & 1) * 8 + kb;
      *reinterpret_cast<uint32_t*>(sF + ks1 * 2080 + off) = du;
      *reinterpret_cast<uint32_t*>(sF + (4 + ks1) * 2080 + off) = pu;
    }
  }
  __syncthreads();

  // ---- MFMA: G[64 pairs][128 h], K=256; B streamed from global (L2 broadcast) ----
  const uint4* Bg = reinterpret_cast<const uint4*>(W1f8);
  f32x4 acc[2][4] = {};
#pragma unroll
  for (int ks = 0; ks < 8; ++ks) {
    uint4 b01 = Bg[((ks * 2 + 0) * 2 + wn) * 64 + lane];
    uint4 b23 = Bg[((ks * 2 + 1) * 2 + wn) * 64 + lane];
    uint4 aa = *reinterpret_cast<const uint4*>(sF + ks * 2080 + wm * 1024 + lane * 16);
    long a0 = mk64(aa.x, aa.y), a1 = mk64(aa.z, aa.w);
    long bb0 = mk64(b01.x, b01.y), bb1 = mk64(b01.z, b01.w);
    long bb2 = mk64(b23.x, b23.y), bb3 = mk64(b23.z, b23.w);
    acc[0][0] = __builtin_amdgcn_mfma_f32_16x16x32_fp8_fp8(a0, bb0, acc[0][0], 0, 0, 0);
    acc[0][1] = __builtin_amdgcn_mfma_f32_16x16x32_fp8_fp8(a0, bb1, acc[0][1], 0, 0, 0);
    acc[0][2] = __builtin_amdgcn_mfma_f32_16x16x32_fp8_fp8(a0, bb2, acc[0][2], 0, 0, 0);
    acc[0][3] = __builtin_amdgcn_mfma_f32_16x16x32_fp8_fp8(a0, bb3, acc[0][3], 0, 0, 0);
    acc[1][0] = __builtin_amdgcn_mfma_f32_16x16x32_fp8_fp8(a1, bb0, acc[1][0], 0, 0, 0);
    acc[1][1] = __builtin_amdgcn_mfma_f32_16x16x32_fp8_fp8(a1, bb1, acc[1][1], 0, 0, 0);
    acc[1][2] = __builtin_amdgcn_mfma_f32_16x16x32_fp8_fp8(a1, bb2, acc[1][2], 0, 0, 0);
    acc[1][3] = __builtin_amdgcn_mfma_f32_16x16x32_fp8_fp8(a1, bb3, acc[1][3], 0, 0, 0);
  }

  __syncthreads();  // sF/sNode dead -> partial-sum buffers
  float(*sPF)[33] = reinterpret_cast<float(*)[33]>(smem);
  float(*sPM)[33] = reinterpret_cast<float(*)[33]>(smem + 16640);

  // ---- two epilogues per pair: fwd L(i,j), mirror L(j,i); Pi/Pj from LDS ----
#pragma unroll
  for (int mi = 0; mi < 2; ++mi) {
#pragma unroll
    for (int r = 0; r < 4; ++r) {
      int p = wm * 32 + mi * 16 + quad * 4 + r;  // C/D: row = quad*4 + reg
      int iRow = wm * 4 + mi * 2 + (quad >> 1);  // ii(p) in 0..7
      int jRow = (quad & 1) * 4 + r;             // jj(p) in 0..7
      float f0 = sScalF[p][0], f1 = sScalF[p][1], f2 = sScalF[p][2], f3 = sScalF[p][3];
      float m0 = sScalM[p][0], m1 = sScalM[p][1], m2 = sScalM[p][2], m3 = sScalM[p][3];
      float vf = 0.f, vm = 0.f;
#pragma unroll
      for (int ni = 0; ni < 4; ++ni) {
        int h = wn * 64 + ni * 16 + col;
        float piI = bf2f(sPP[(0 + iRow) * 136 + h]);
        float piJ = bf2f(sPP[(8 + jRow) * 136 + h]);
        float pjI = bf2f(sPP[(16 + iRow) * 136 + h]);
        float pjJ = bf2f(sPP[(24 + jRow) * 136 + h]);
        float gv = acc[mi][ni][r] * INV256;
        float pf = (gv + piI) + pjJ;
        pf = fmaf(f0, cB0[ni], pf);
        pf = fmaf(f1, cB1[ni], pf);
        pf = fmaf(f2, cB2[ni], pf);
        pf = fmaf(f3, cB3[ni], pf);
        float pm = (gv + piJ) + pjI;
        pm = fmaf(m0, cB0[ni], pm);
        pm = fmaf(m1, cB1[ni], pm);
        pm = fmaf(m2, cB2[ni], pm);
        pm = fmaf(m3, cB3[ni], pm);
        vf = fmaf(fmaxf(pf, 0.f), cW2[ni], vf);
        vm = fmaf(fmaxf(pm, 0.f), cW2[ni], vm);
      }
      sPF[p][wn * 16 + col] = vf;
      sPM[p][wn * 16 + col] = vm;
    }
  }
  __syncthreads();
  if (tid < 64) {
    int p = tid;
    float sumF = 0.f, sumM = 0.f;
#pragma unroll
    for (int c = 0; c < 32; ++c) {
      sumF += sPF[p][c];
      sumM += sPM[p][c];
    }
    float val = 0.5f * (sumF + sumM) + b2v;
    int iN = I0 + (p >> 3), jN = J0 + (p & 7);
    if (iN == jN) {
      out[(size_t)(rowB + iN) * 256 + jN] = -1e9f;
    } else {
      out[(size_t)(rowB + iN) * 256 + jN] = val;
      out[(size_t)(rowB + jN) * 256 + iN] = val;
    }
  }
}

extern "C" void kernel_launch(void* const* d_in, const int* in_sizes, int n_in,
                              void* d_out, int out_size, void* d_ws, size_t ws_size,
                              hipStream_t stream) {
  const float* node = (const float*)d_in[0];   // [4,256,128]
  const float* baseL = (const float*)d_in[1];  // [4,256,256]
  const float* compL = (const float*)d_in[2];  // [4,256,256]
  const float* W1 = (const float*)d_in[3];     // [516,128]
  const float* b1 = (const float*)d_in[4];     // [128]
  const float* W2 = (const float*)d_in[5];     // [128,1]
  const float* b2 = (const float*)d_in[6];     // [1]
  float* out = (float*)d_out;                  // [4,256,256] fp32

  char* ws = (char*)d_ws;
  float* PiB = (float*)(ws);                              // 512 KB
  float* Pjf = (float*)(ws + (512 << 10));                // 512 KB
  uint32_t* W1f8 = (uint32_t*)(ws + (1024 << 10));        // 32 KB

  pre_k<<<1056, 128, 0, stream>>>(node, W1, b1, PiB, Pjf, W1f8);
  main_k<<<2112, 256, 0, stream>>>(node, baseL, compL, W1, W2, b2, W1f8, PiB, Pjf, out);
}